// Round 12
// baseline (84.503 us; speedup 1.0000x reference)
//
#include <hip/hip_runtime.h>
#include <math.h>

// Chamfer loss, B=32, N=2048, 3 used components.
// R12 = R10 (79.1 us champion) with x2/y2 moved INTO the MFMA K-slots:
// d2 = x2 + y2 - 2 p.q entirely inside one v_mfma_f32_32x32x16_bf16, C = 0.
// Slot map (k = 8*half + si; A and B share it -> sum invariant):
//   lo half si0..7: A=[phx,phy,phz, plx,ply,plz, phx,phy]
//                   B=[ghx,ghy,ghz, ghx,ghy,ghz, glx,gly]
//   hi half si0..7: A=[phz, x2h, x2l, 1, 1, 0,0,0]
//                   B=[glz, 1,   1, y2h, y2l, 0,0,0]
// where g=-2q, *h/*l = bf16 hi/lo split (dropped terms ~2e-5; R10 measured
// absmax 0.0 with the same split). Removes the 16 C-seed adds/iter, the cin
// register block, sy2/sx2 LDS, and the x2s array -> ~70 live VGPR, no spill.
// B-frags unified in sfrag[2][1024] -> per-iter B load is ONE ds_read_b128.
// Block = 128 rows x 1024 cols, grid (16,2,32) = 1024 blocks, 4/CU.
// Col mins via LDS atomicMin (uint-cast, clamped); row mins in-register ->
// shfl reduce. Single-writer global partials (no init, no global atomics):
// ws_row[b][bi][jh][128] 512KB, ws_col[b][jh][bi][1024] 4MB. Sum kernel
// merges, sqrt, 0.5*sum. 2 dispatches, zero memsets.

#define NPTS   2048
#define NBATCH 32
#define NBI    16                      // 128-row chunks
#define NJH    2                       // 1024-col halves
#define WS_ROW_FLOATS ((size_t)NBATCH * NBI * NJH * 128)   // 131072 floats
#define EPSF   1e-16f
#define BIGF   3.4e38f
#define ONEBF  0x3F80u                 // bf16 1.0

typedef __attribute__((ext_vector_type(8)))  short bf16x8;
typedef __attribute__((ext_vector_type(16))) float f32x16;
typedef __attribute__((ext_vector_type(4)))  unsigned int u32x4;

__device__ __forceinline__ float min3f(float a, float b, float c) {
    return fminf(fminf(a, b), c);      // -> v_min3_f32
}
__device__ __forceinline__ unsigned short bf16_rne(float f) {
    unsigned int u = __float_as_uint(f);
    return (unsigned short)((u + 0x7FFFu + ((u >> 16) & 1u)) >> 16);
}
__device__ __forceinline__ float bf16_f32(unsigned short h) {
    return __uint_as_float(((unsigned int)h) << 16);
}

__global__ __launch_bounds__(256, 4) void chamfer_mfma_kernel(
    const float* __restrict__ P, const float* __restrict__ Q,
    float* __restrict__ ws, float* __restrict__ out)
{
    __shared__ u32x4        sfrag[2][1024];  // B-frags lo/hi halves (32KB)
    __shared__ unsigned int scol[1024];      // col-min, uint-cast (4KB)
    __shared__ float        srow[128];       // row-min funnel (512B)

    const int tid  = threadIdx.x;
    const int lane = tid & 63;
    const int wv   = tid >> 6;
    const int l31  = lane & 31;
    const int hi   = lane >> 5;        // k-half select
    const int bi   = blockIdx.x;       // 128-row chunk
    const int jh   = blockIdx.y;       // 1024-col half
    const int b    = blockIdx.z;       // batch

    if (bi == 0 && jh == 0 && b == 0 && tid == 0) *out = 0.f;

    // ---- stage q half: 4 cols/thread -> split bf16 B-frags (both halves)
    {
        const float4* Qb = (const float4*)Q + (size_t)b * NPTS + jh * 1024;
        #pragma unroll
        for (int s = 0; s < 4; ++s) {
            int c = tid + 256 * s;
            float4 qv = Qb[c];
            float gx = -2.f * qv.y, gy = -2.f * qv.z, gz = -2.f * qv.w;
            unsigned short hx = bf16_rne(gx), hy = bf16_rne(gy), hz = bf16_rne(gz);
            unsigned short lx = bf16_rne(gx - bf16_f32(hx));
            unsigned short ly = bf16_rne(gy - bf16_f32(hy));
            unsigned short lz = bf16_rne(gz - bf16_f32(hz));
            float y2 = fmaf(qv.y, qv.y, fmaf(qv.z, qv.z, qv.w * qv.w));
            unsigned short y2h = bf16_rne(y2);
            unsigned short y2l = bf16_rne(y2 - bf16_f32(y2h));
            // lo half: [ghx,ghy,ghz, ghx,ghy,ghz, glx,gly]
            sfrag[0][c] = (u32x4){ (unsigned)hx | ((unsigned)hy << 16),
                                   (unsigned)hz | ((unsigned)hx << 16),
                                   (unsigned)hy | ((unsigned)hz << 16),
                                   (unsigned)lx | ((unsigned)ly << 16) };
            // hi half: [glz, 1, 1, y2h, y2l, 0, 0, 0]
            sfrag[1][c] = (u32x4){ (unsigned)lz | (ONEBF << 16),
                                   ONEBF | ((unsigned)y2h << 16),
                                   (unsigned)y2l,
                                   0u };
            scol[c] = 0x7F7F7F7Fu;
        }
    }

    // ---- A-frag: my row (lanes l and l+32 share row, different k-half)
    bf16x8 afrag;
    {
        const int rowl = wv * 32 + l31;
        float4 pv = ((const float4*)P)[(size_t)b * NPTS + bi * 128 + rowl];
        float x = pv.y, y = pv.z, z = pv.w;
        unsigned short hx = bf16_rne(x), hy = bf16_rne(y), hz = bf16_rne(z);
        unsigned short lx = bf16_rne(x - bf16_f32(hx));
        unsigned short ly = bf16_rne(y - bf16_f32(hy));
        unsigned short lz = bf16_rne(z - bf16_f32(hz));
        float x2 = fmaf(x, x, fmaf(y, y, z * z));
        unsigned short x2h = bf16_rne(x2);
        unsigned short x2l = bf16_rne(x2 - bf16_f32(x2h));
        u32x4 araw;
        if (hi == 0)   // [phx,phy,phz, plx,ply,plz, phx,phy]
            araw = (u32x4){ (unsigned)hx | ((unsigned)hy << 16),
                            (unsigned)hz | ((unsigned)lx << 16),
                            (unsigned)ly | ((unsigned)lz << 16),
                            (unsigned)hx | ((unsigned)hy << 16) };
        else           // [phz, x2h, x2l, 1, 1, 0, 0, 0]
            araw = (u32x4){ (unsigned)hz | ((unsigned)x2h << 16),
                            (unsigned)x2l | (ONEBF << 16),
                            ONEBF,
                            0u };
        afrag = __builtin_bit_cast(bf16x8, araw);
    }
    __syncthreads();

    // ---- sweep 32 col-tiles of 32; D = full d2 (C = 0)
    const u32x4* bbase = &sfrag[hi][0];
    f32x16 cz;
    #pragma unroll
    for (int r = 0; r < 16; ++r) cz[r] = 0.f;

    float rowacc[16];
    #pragma unroll
    for (int r = 0; r < 16; ++r) rowacc[r] = BIGF;

    for (int t = 0; t < 32; ++t) {
        const int c = t * 32 + l31;
        bf16x8 bfrag = __builtin_bit_cast(bf16x8, bbase[c]);

        f32x16 d = __builtin_amdgcn_mfma_f32_32x32x16_bf16(afrag, bfrag, cz,
                                                           0, 0, 0);
        #pragma unroll
        for (int r = 0; r < 16; ++r) rowacc[r] = fminf(rowacc[r], d[r]);

        // col-min over my 16 rows, merge halves, publish via LDS atomic
        float m = fminf(min3f(min3f(d[0], d[1], d[2]),
                              min3f(d[3], d[4], d[5]),
                              min3f(d[6], d[7], d[8])),
                        min3f(min3f(d[9], d[10], d[11]),
                              min3f(d[12], d[13], d[14]), d[15]));
        m = fminf(m, __shfl_xor(m, 32));
        if (hi == 0)
            atomicMin(&scol[c], __float_as_uint(fmaxf(m, 0.f)));
    }

    // ---- row epilogue: reduce across 32 lanes of each half
    #pragma unroll
    for (int r = 0; r < 16; ++r) {
        float v = rowacc[r];
        v = fminf(v, __shfl_xor(v, 1));
        v = fminf(v, __shfl_xor(v, 2));
        v = fminf(v, __shfl_xor(v, 4));
        v = fminf(v, __shfl_xor(v, 8));
        v = fminf(v, __shfl_xor(v, 16));
        rowacc[r] = v;
    }
    if (l31 == 0) {                    // lanes 0 and 32 of each wave
        #pragma unroll
        for (int r = 0; r < 16; ++r)
            srow[wv * 32 + 4 * hi + (r & 3) + 8 * (r >> 2)] = rowacc[r];
    }
    __syncthreads();

    // ---- single-writer global partials (coalesced)
    if (tid < 128)
        ws[(((size_t)b * NBI + bi) * NJH + jh) * 128 + tid] = srow[tid];
    {
        float* cbase = ws + WS_ROW_FLOATS
                     + (((size_t)b * NJH + jh) * NBI + bi) * 1024;
        #pragma unroll
        for (int s = 0; s < 4; ++s) {
            int c = tid + 256 * s;
            cbase[c] = __uint_as_float(scol[c]);   // full d2, clamped >= 0
        }
    }
}

__global__ __launch_bounds__(256) void chamfer_sum_kernel(
    const float* __restrict__ ws, float* __restrict__ out)
{
    __shared__ float rbuf[4];
    const int tid = threadIdx.x;
    const int i   = blockIdx.x * 256 + tid;   // 0..65535
    const int b   = i >> 11;
    const int e   = i & 2047;

    // row side: min over 2 jh partials
    float s;
    {
        const int bi = e >> 7, el = e & 127;
        const float* rb = ws + ((size_t)(b * NBI + bi) * NJH) * 128 + el;
        float v = fminf(rb[0], rb[128]);
        s = sqrtf(fmaxf(v, 0.f) + EPSF);
    }
    // col side: min over 16 bi partials (coalesced in el)
    {
        const int jh = e >> 10, el = e & 1023;
        const float* cb = ws + WS_ROW_FLOATS
                        + ((size_t)(b * NJH + jh) * NBI) * 1024 + el;
        float v = BIGF;
        #pragma unroll
        for (int j = 0; j < NBI; ++j) v = fminf(v, cb[(size_t)j * 1024]);
        s += sqrtf(fmaxf(v, 0.f) + EPSF);
    }

    #pragma unroll
    for (int off = 32; off > 0; off >>= 1) s += __shfl_down(s, off);
    if ((tid & 63) == 0) rbuf[tid >> 6] = s;
    __syncthreads();
    if (tid == 0)
        atomicAdd(out, 0.5f * ((rbuf[0] + rbuf[1]) + (rbuf[2] + rbuf[3])));
}

extern "C" void kernel_launch(void* const* d_in, const int* in_sizes, int n_in,
                              void* d_out, int out_size, void* d_ws, size_t ws_size,
                              hipStream_t stream) {
    const float* P = (const float*)d_in[0];   // p[0] = first 32*2048*4 floats
    const float* Q = (const float*)d_in[1];
    float* out = (float*)d_out;
    float* ws  = (float*)d_ws;                // uses 4.5 MiB

    dim3 grid(NBI, NJH, NBATCH);              // 16 x 2 x 32 = 1024 blocks
    chamfer_mfma_kernel<<<grid, 256, 0, stream>>>(P, Q, ws, out);
    chamfer_sum_kernel<<<256, 256, 0, stream>>>(ws, out);
}

// Round 13
// 80.277 us; speedup vs baseline: 1.0527x; 1.0527x over previous
//
#include <hip/hip_runtime.h>
#include <math.h>

// Chamfer loss, B=32, N=2048, 3 used components.
// R13: 16x16x32 MFMA, full bf16-split, tiny register footprint.
// d2 = x2 + y2 + p.(-2q) computed ENTIRELY inside v_mfma_f32_16x16x32_bf16
// (C = 0). K=32 slots, g = lane>>4 selects slot-group of 8 (A,B symmetric;
// k-permutation-robust packing, HW-validated by R10's absmax 0.0):
//   g0: A=[phx,phy,phz, plx,ply,plz, x2h,x2l] B=[ghx,ghy,ghz, glx,gly,glz, 1,1]
//   g1: A=[phx,phy,phz, 1,1, 0,0,0]           B=[glx,gly,glz, y2h,y2l, 0,0,0]
//   g2: A=[plx,ply,plz, 0..]                  B=[ghx,ghy,ghz, 0..]
//   g3: A=0 (B read from g2 array, don't-care)
// Sum = x2 + y2 + (ph+pl).(gh+gl) -- ALL four split products (more accurate
// than R10). C/D layout (m89/m91 verified): col=lane&15, row=(lane>>4)*4+reg.
// Why: R10/R12's 32x32 path held 60+ acc VGPRs -> spills at the (256,4) cap
// (R12 removing VALU but regressing = spill signature). Here d=4, acc=2x4,
// frags 3x4 -> ~50 live VGPR, spill-proof, 4 blocks/CU.
// Block = 128 rows x 512 cols; wave = 32 rows (2 MFMAs); 32 col-tiles.
// Col mins via LDS atomicMin; row mins in-reg -> shfl -> funnel. Exact
// single-writer partials (no init, no global atomics): ws_row[b][bi][jc][128]
// 1MB, ws_col[b][jc][bi][512] 4MB. Sum kernel merges, sqrt, 0.5*sum.
// 2 dispatches, zero memsets.

#define NPTS   2048
#define NBATCH 32
#define BROWS  128
#define BCOLS  512
#define NBI    (NPTS / BROWS)          // 16
#define NJC    (NPTS / BCOLS)          // 4
#define WS_ROW_FLOATS ((size_t)NBATCH * NBI * NJC * BROWS)   // 262144 floats
#define EPSF   1e-16f
#define BIGF   3.4e38f
#define ONEBF  0x3F80u                 // bf16 1.0

typedef __attribute__((ext_vector_type(8))) short bf16x8;
typedef __attribute__((ext_vector_type(4))) float f32x4;
typedef __attribute__((ext_vector_type(4))) unsigned int u32x4;

__device__ __forceinline__ float min3f(float a, float b, float c) {
    return fminf(fminf(a, b), c);      // -> v_min3_f32
}
__device__ __forceinline__ unsigned short bf16_rne(float f) {
    unsigned int u = __float_as_uint(f);
    return (unsigned short)((u + 0x7FFFu + ((u >> 16) & 1u)) >> 16);
}
__device__ __forceinline__ float bf16_f32(unsigned short h) {
    return __uint_as_float(((unsigned int)h) << 16);
}

__global__ __launch_bounds__(256, 4) void chamfer_mfma_kernel(
    const float* __restrict__ P, const float* __restrict__ Q,
    float* __restrict__ ws, float* __restrict__ out)
{
    __shared__ u32x4        sB0[BCOLS];   // B-frag group0 (8 KB)
    __shared__ u32x4        sB1[BCOLS];   // B-frag group1 (8 KB)
    __shared__ u32x4        sB2[BCOLS];   // B-frag group2 (8 KB)
    __shared__ unsigned int scol[BCOLS];  // col-min, uint-cast (2 KB)
    __shared__ float        srow[BROWS];  // row-min funnel (0.5 KB)

    const int tid  = threadIdx.x;
    const int lane = tid & 63;
    const int wv   = tid >> 6;
    const int c15  = lane & 15;        // col-in-tile / row-in-tile
    const int g    = lane >> 4;        // k slot-group 0..3
    const int bi   = blockIdx.x;       // 128-row chunk
    const int jc   = blockIdx.y;       // 512-col chunk
    const int b    = blockIdx.z;       // batch

    if (bi == 0 && jc == 0 && b == 0 && tid == 0) *out = 0.f;

    // ---- stage B frags: 2 cols/thread
    {
        const float4* Qb = (const float4*)Q + (size_t)b * NPTS + jc * BCOLS;
        #pragma unroll
        for (int s = 0; s < 2; ++s) {
            int c = tid + 256 * s;
            float4 qv = Qb[c];
            float gx = -2.f * qv.y, gy = -2.f * qv.z, gz = -2.f * qv.w;
            unsigned short hx = bf16_rne(gx), hy = bf16_rne(gy), hz = bf16_rne(gz);
            unsigned short lx = bf16_rne(gx - bf16_f32(hx));
            unsigned short ly = bf16_rne(gy - bf16_f32(hy));
            unsigned short lz = bf16_rne(gz - bf16_f32(hz));
            float y2 = fmaf(qv.y, qv.y, fmaf(qv.z, qv.z, qv.w * qv.w));
            unsigned short y2h = bf16_rne(y2);
            unsigned short y2l = bf16_rne(y2 - bf16_f32(y2h));
            sB0[c] = (u32x4){ (unsigned)hx | ((unsigned)hy << 16),
                              (unsigned)hz | ((unsigned)lx << 16),
                              (unsigned)ly | ((unsigned)lz << 16),
                              ONEBF | (ONEBF << 16) };
            sB1[c] = (u32x4){ (unsigned)lx | ((unsigned)ly << 16),
                              (unsigned)lz | ((unsigned)y2h << 16),
                              (unsigned)y2l, 0u };
            sB2[c] = (u32x4){ (unsigned)hx | ((unsigned)hy << 16),
                              (unsigned)hz, 0u, 0u };
            scol[c] = 0x7F7F7F7Fu;
        }
    }

    // ---- A frags for my 2 rows (MFMA0: wave rows 0-15, MFMA1: 16-31)
    bf16x8 afrag0, afrag1;
    {
        const float4* Pb = (const float4*)P + (size_t)b * NPTS
                         + bi * BROWS + wv * 32;
        #pragma unroll
        for (int h = 0; h < 2; ++h) {
            float4 pv = Pb[h * 16 + c15];
            float x = pv.y, y = pv.z, z = pv.w;
            unsigned short hx = bf16_rne(x), hy = bf16_rne(y), hz = bf16_rne(z);
            unsigned short lx = bf16_rne(x - bf16_f32(hx));
            unsigned short ly = bf16_rne(y - bf16_f32(hy));
            unsigned short lz = bf16_rne(z - bf16_f32(hz));
            float x2 = fmaf(x, x, fmaf(y, y, z * z));
            unsigned short x2h = bf16_rne(x2);
            unsigned short x2l = bf16_rne(x2 - bf16_f32(x2h));
            u32x4 a;
            if (g == 0)
                a = (u32x4){ (unsigned)hx | ((unsigned)hy << 16),
                             (unsigned)hz | ((unsigned)lx << 16),
                             (unsigned)ly | ((unsigned)lz << 16),
                             (unsigned)x2h | ((unsigned)x2l << 16) };
            else if (g == 1)
                a = (u32x4){ (unsigned)hx | ((unsigned)hy << 16),
                             (unsigned)hz | (ONEBF << 16),
                             ONEBF, 0u };
            else if (g == 2)
                a = (u32x4){ (unsigned)lx | ((unsigned)ly << 16),
                             (unsigned)lz, 0u, 0u };
            else
                a = (u32x4){ 0u, 0u, 0u, 0u };
            if (h == 0) afrag0 = __builtin_bit_cast(bf16x8, a);
            else        afrag1 = __builtin_bit_cast(bf16x8, a);
        }
    }
    __syncthreads();

    // ---- main loop: 32 col-tiles of 16; D = full d2 (C = 0)
    const u32x4* bbase = (g == 0) ? sB0 : (g == 1) ? sB1 : sB2;  // g3 -> sB2 (A=0)
    const f32x4 cz = {0.f, 0.f, 0.f, 0.f};
    float ra0[4], ra1[4];
    #pragma unroll
    for (int r = 0; r < 4; ++r) { ra0[r] = BIGF; ra1[r] = BIGF; }

    #pragma unroll 2
    for (int t = 0; t < BCOLS / 16; ++t) {
        bf16x8 bfrag = __builtin_bit_cast(bf16x8, bbase[t * 16 + c15]);
        f32x4 d0 = __builtin_amdgcn_mfma_f32_16x16x32_bf16(afrag0, bfrag, cz, 0, 0, 0);
        f32x4 d1 = __builtin_amdgcn_mfma_f32_16x16x32_bf16(afrag1, bfrag, cz, 0, 0, 0);
        #pragma unroll
        for (int r = 0; r < 4; ++r) {
            ra0[r] = fminf(ra0[r], d0[r]);
            ra1[r] = fminf(ra1[r], d1[r]);
        }
        // col-min over this wave's 32 rows for col t*16 + (lane&15)
        float m = min3f(min3f(d0[0], d0[1], d0[2]),
                        min3f(d0[3], d1[0], d1[1]),
                        fminf(d1[2], d1[3]));
        m = fminf(m, __shfl_xor(m, 16));   // merge g-bit0
        m = fminf(m, __shfl_xor(m, 32));   // merge g-bit1
        if (lane < 16)
            atomicMin(&scol[t * 16 + lane], __float_as_uint(fmaxf(m, 0.f)));
    }

    // ---- row epilogue: min over cols = reduce across c15 bits
    #pragma unroll
    for (int r = 0; r < 4; ++r) {
        float v0 = ra0[r], v1 = ra1[r];
        v0 = fminf(v0, __shfl_xor(v0, 1)); v1 = fminf(v1, __shfl_xor(v1, 1));
        v0 = fminf(v0, __shfl_xor(v0, 2)); v1 = fminf(v1, __shfl_xor(v1, 2));
        v0 = fminf(v0, __shfl_xor(v0, 4)); v1 = fminf(v1, __shfl_xor(v1, 4));
        v0 = fminf(v0, __shfl_xor(v0, 8)); v1 = fminf(v1, __shfl_xor(v1, 8));
        if (c15 == 0) {                    // lanes 0,16,32,48: row g*4+r
            srow[wv * 32 + g * 4 + r]      = v0;
            srow[wv * 32 + 16 + g * 4 + r] = v1;
        }
    }
    __syncthreads();

    // ---- single-writer global partials (coalesced)
    if (tid < BROWS)
        ws[(((size_t)b * NBI + bi) * NJC + jc) * BROWS + tid] = srow[tid];
    {
        float* cb = ws + WS_ROW_FLOATS
                  + (((size_t)b * NJC + jc) * NBI + bi) * BCOLS;
        #pragma unroll
        for (int s = 0; s < 2; ++s) {
            int c = tid + 256 * s;
            cb[c] = __uint_as_float(scol[c]);   // clamped >= 0 already
        }
    }
}

__global__ __launch_bounds__(256) void chamfer_sum_kernel(
    const float* __restrict__ ws, float* __restrict__ out)
{
    __shared__ float rbuf[4];
    const int tid = threadIdx.x;
    const int i   = blockIdx.x * 256 + tid;   // 0..65535
    const int b   = i >> 11;
    const int e   = i & 2047;

    // row side: min over 4 jc partials
    float s;
    {
        const int bi = e >> 7, rl = e & 127;
        const float* rb = ws + ((size_t)(b * NBI + bi) * NJC) * BROWS + rl;
        float v = fminf(fminf(rb[0], rb[BROWS]),
                        fminf(rb[2 * BROWS], rb[3 * BROWS]));
        s = sqrtf(fmaxf(v, 0.f) + EPSF);
    }
    // col side: min over 16 bi partials (coalesced in cl)
    {
        const int jcx = e >> 9, cl = e & 511;
        const float* cb = ws + WS_ROW_FLOATS
                        + ((size_t)(b * NJC + jcx) * NBI) * BCOLS + cl;
        float v = BIGF;
        #pragma unroll
        for (int j = 0; j < NBI; ++j) v = fminf(v, cb[(size_t)j * BCOLS]);
        s += sqrtf(fmaxf(v, 0.f) + EPSF);
    }

    #pragma unroll
    for (int off = 32; off > 0; off >>= 1) s += __shfl_down(s, off);
    if ((tid & 63) == 0) rbuf[tid >> 6] = s;
    __syncthreads();
    if (tid == 0)
        atomicAdd(out, 0.5f * ((rbuf[0] + rbuf[1]) + (rbuf[2] + rbuf[3])));
}

extern "C" void kernel_launch(void* const* d_in, const int* in_sizes, int n_in,
                              void* d_out, int out_size, void* d_ws, size_t ws_size,
                              hipStream_t stream) {
    const float* P = (const float*)d_in[0];   // p[0] = first 32*2048*4 floats
    const float* Q = (const float*)d_in[1];
    float* out = (float*)d_out;
    float* ws  = (float*)d_ws;                // uses ~5.2 MiB

    dim3 grid(NBI, NJC, NBATCH);              // 16 x 4 x 32 = 2048 blocks
    chamfer_mfma_kernel<<<grid, 256, 0, stream>>>(P, Q, ws, out);
    chamfer_sum_kernel<<<256, 256, 0, stream>>>(ws, out);
}